// Round 19
// baseline (819.085 us; speedup 1.0000x reference)
//
#include <hip/hip_runtime.h>
#include <stdint.h>

// BasicNCA2D: 10 steps of depthwise7x7(reflect) -> concat -> fc0 -> BN(batch) -> relu -> fc1 -> masked update.
// B=8,H=256,W=256,C=16,HID=128. steps hardcoded to 10.
// RNG: JAX threefry, jax_threefry_partitionable=True: bits[i] = xor(threefry2x32(key,(0,i))).
//
// R18: (a) convgram pack phase no longer re-reads center-x from global (8x stride-64B
// float4/thread, R13's L1-line-touch pattern): center is captured from the r==j+3,dx==3
// tap registers during the conv loop (bit-identical values). (b) reduceA+reduceB fused
// via last-block pattern (threadfence + device atomicAdd + acquire); per-step counters
// zeroed by one hipMemsetAsync at launch start (graph-safe). Saves a launch/step.

constexpr int Bn = 8;
constexpr int Hn = 256;
constexpr int Wn = 256;
constexpr int Cn = 16;
constexpr int HIDn = 128;
constexpr int NCELLS = Bn * Hn * Wn;       // 524288
constexpr int NGRP = 1024;                 // fused conv+gram blocks (512 cells each)
constexpr int NPAIR = 528;                 // 32*33/2 unique second moments of y
constexpr int NSTAT = 560;                 // pairs + 32 first moments
constexpr int STEPS = 10;
constexpr int RCELLS = 134;                // staged row cells: 128 + 2*3 halo
constexpr int NRED = 140;                  // reduce blocks (4 stats each)

typedef __attribute__((ext_vector_type(8))) short bf16x8;
typedef __attribute__((ext_vector_type(4))) float f32x4;
typedef __attribute__((ext_vector_type(2))) float f32x2;

__host__ __device__ inline uint32_t rotl32(uint32_t v, int r) {
  return (v << r) | (v >> (32 - r));
}

// Threefry-2x32, 20 rounds, exactly as jax/_src/prng.py
__host__ __device__ inline void tf2x32(uint32_t k0, uint32_t k1,
                                       uint32_t& x0, uint32_t& x1) {
  uint32_t k2 = k0 ^ k1 ^ 0x1BD11BDAu;
  x0 += k0; x1 += k1;
  x0 += x1; x1 = rotl32(x1, 13); x1 ^= x0;
  x0 += x1; x1 = rotl32(x1, 15); x1 ^= x0;
  x0 += x1; x1 = rotl32(x1, 26); x1 ^= x0;
  x0 += x1; x1 = rotl32(x1,  6); x1 ^= x0;
  x0 += k1; x1 += k2 + 1u;
  x0 += x1; x1 = rotl32(x1, 17); x1 ^= x0;
  x0 += x1; x1 = rotl32(x1, 29); x1 ^= x0;
  x0 += x1; x1 = rotl32(x1, 16); x1 ^= x0;
  x0 += x1; x1 = rotl32(x1, 24); x1 ^= x0;
  x0 += k2; x1 += k0 + 2u;
  x0 += x1; x1 = rotl32(x1, 13); x1 ^= x0;
  x0 += x1; x1 = rotl32(x1, 15); x1 ^= x0;
  x0 += x1; x1 = rotl32(x1, 26); x1 ^= x0;
  x0 += x1; x1 = rotl32(x1,  6); x1 ^= x0;
  x0 += k0; x1 += k1 + 3u;
  x0 += x1; x1 = rotl32(x1, 17); x1 ^= x0;
  x0 += x1; x1 = rotl32(x1, 29); x1 ^= x0;
  x0 += x1; x1 = rotl32(x1, 16); x1 ^= x0;
  x0 += x1; x1 = rotl32(x1, 24); x1 ^= x0;
  x0 += k1; x1 += k2 + 4u;
  x0 += x1; x1 = rotl32(x1, 13); x1 ^= x0;
  x0 += x1; x1 = rotl32(x1, 15); x1 ^= x0;
  x0 += x1; x1 = rotl32(x1, 26); x1 ^= x0;
  x0 += x1; x1 = rotl32(x1,  6); x1 ^= x0;
  x0 += k2; x1 += k0 + 5u;
}

__device__ inline float cell_mask(uint32_t fk0, uint32_t fk1, uint32_t ci) {
  uint32_t a = 0u, b2 = ci;
  tf2x32(fk0, fk1, a, b2);
  uint32_t bits = a ^ b2;
  float u = __uint_as_float((bits >> 9) | 0x3f800000u) - 1.0f;
  return (u > 0.5f) ? 1.0f : 0.0f;
}

// fp32 -> bf16 bits, round-to-nearest-even
__device__ inline uint32_t f2bf(float f) {
  uint32_t u = __float_as_uint(f);
  return (u + 0x7fffu + ((u >> 16) & 1u)) >> 16;
}

// one-time prep:
//  w0bf [n=128][k=32] bf16 : w0bf[n*32+k] = bf16(fc0w[k*128+n])
//  w1p  [c=16][kl=128] bf16: n = (kl&7)*16 + (kl>>3); w1p[c*128+kl] = bf16(fc1w[n*16+c])
__global__ __launch_bounds__(256) void nca_prep(const float* __restrict__ fc0w,
                                                const float* __restrict__ fc1w,
                                                uint16_t* __restrict__ w0bf,
                                                uint16_t* __restrict__ w1p) {
  int i = blockIdx.x * 256 + threadIdx.x;  // 0..6143
  if (i < 4096) {
    int n = i >> 5, k = i & 31;
    w0bf[i] = (uint16_t)f2bf(fc0w[k * HIDn + n]);
  } else {
    int j = i - 4096;
    int c = j >> 7, kl = j & 127;
    int n = (kl & 7) * 16 + (kl >> 3);
    w1p[j] = (uint16_t)f2bf(fc1w[n * 16 + c]);
  }
}

// swizzled float-index of the 16B unit (cell c, quad q) in a staged row
__device__ inline int row_fi(int c, int q) {
  return (((c << 6) + (q << 4)) ^ ((c & 7) << 4)) >> 2;
}

// Fused conv+gram with LDS row staging (R15 structure). Block = (b, h-strip of 4,
// w-half of 128): 512 cells, 256 threads (128 cols x 2 ch-halves of 8). Rows staged
// into a double-buffered swizzled sRow; taps via ds_read_b128; conv FMAs packed
// (v_pk_fma_f32); center-x captured from tap registers (r==j+3, dx==3).
// Gram: two rounds through 16KB sYT.
__global__ __launch_bounds__(256, 4) void nca_convgram(
    const float* __restrict__ x, const float* __restrict__ p0w,
    const float* __restrict__ p0b, uint16_t* __restrict__ ybf,
    float* __restrict__ partials) {
  __shared__ float sW[784];
  __shared__ float sB[16];
  __shared__ __align__(16) float sRow[2][RCELLS * 16];   // 2 x 8576B, swizzled
  __shared__ __align__(16) short sYT[32 * 256];          // 16KB; aliased as f32 gram[4][1024]
  __shared__ float sMom[4 * 32];
  int t = threadIdx.x;
  int lane = t & 63, wid = t >> 6;
  int bid = blockIdx.x;
  int b = bid & 7;               // one image per XCD
  int rest = bid >> 3;           // 0..127
  int h0 = (rest >> 1) * 4;
  int wbase = (rest & 1) * 128;
  for (int i = t; i < 784; i += 256) sW[i] = p0w[i];
  if (t < 16) sB[t] = p0b[t];

  int wl = t & 127;
  int half = t >> 7;             // 0 or 1
  int ch0 = half * 8;
  int w = wbase + wl;
  const float* xb = x + (size_t)b * (Hn * Wn * Cn);

  // global row pointer with vertical reflect
  auto rowptr = [&](int r) -> const float* {
    int hi = h0 - 3 + r;
    hi = (hi < 0) ? -hi : ((hi >= Hn) ? (2 * Hn - 2 - hi) : hi);
    return xb + (size_t)hi * (Wn * Cn);
  };
  // load 16B unit i (cell i>>2, quad i&3) of a row, horizontal reflect
  auto ld16 = [&](const float* xr, int i) -> float4 {
    int c = i >> 2, q = i & 3;
    int wc = wbase - 3 + c;
    wc = (wc < 0) ? -wc : ((wc >= Wn) ? (2 * Wn - 2 - wc) : wc);
    return *reinterpret_cast<const float4*>(xr + (size_t)wc * Cn + q * 4);
  };

  // stage row 0 into buf 0  (536 = 134*4 16B-units, 256 threads: i, i+256, i+512)
  {
    const float* xr = rowptr(0);
    float4 p0 = ld16(xr, t);
    float4 p1 = ld16(xr, t + 256);
    float4 p2;
    if (t < 536 - 512) p2 = ld16(xr, t + 512);
    float* rb = sRow[0];
    *reinterpret_cast<float4*>(rb + row_fi(t >> 2, t & 3)) = p0;
    *reinterpret_cast<float4*>(rb + row_fi((t + 256) >> 2, t & 3)) = p1;
    if (t < 536 - 512)
      *reinterpret_cast<float4*>(rb + row_fi((t + 512) >> 2, t & 3)) = p2;
  }
  __syncthreads();

  f32x2 acc2[4][4];
  f32x2 xc2[4][4];  // center x per cell (captured from taps, bit-identical)
#pragma unroll
  for (int j = 0; j < 4; j++)
#pragma unroll
    for (int c = 0; c < 4; c++) acc2[j][c] = (f32x2){0.0f, 0.0f};

#pragma unroll 1
  for (int r = 0; r < 10; r++) {
    int cur = r & 1;
    // issue next row's global loads early (latency hides under taps+FMA)
    float4 p0, p1, p2;
    if (r < 9) {
      const float* xr = rowptr(r + 1);
      p0 = ld16(xr, t);
      p1 = ld16(xr, t + 256);
      if (t < 536 - 512) p2 = ld16(xr, t + 512);
    }
    // consume current row taps from LDS (packed fp32 FMAs)
    const float* rb = sRow[cur];
#pragma unroll
    for (int dx = 0; dx < 7; dx++) {
      int c = wl + dx;
      float4 va = *reinterpret_cast<const float4*>(rb + row_fi(c, 2 * half));
      float4 vb = *reinterpret_cast<const float4*>(rb + row_fi(c, 2 * half + 1));
      f32x2 v2[4];
      v2[0] = (f32x2){va.x, va.y}; v2[1] = (f32x2){va.z, va.w};
      v2[2] = (f32x2){vb.x, vb.y}; v2[3] = (f32x2){vb.z, vb.w};
      if (dx == 3) {  // center column: capture x for cell j when r == j+3
#pragma unroll
        for (int j = 0; j < 4; j++) {
          if (r == j + 3) {
#pragma unroll
            for (int c2 = 0; c2 < 4; c2++) xc2[j][c2] = v2[c2];
          }
        }
      }
#pragma unroll
      for (int j = 0; j < 4; j++) {
        if (r >= j && r <= j + 6) {  // cell j taps dy = r-j (wave-uniform branch)
          const f32x2* wt2 = reinterpret_cast<const f32x2*>(
              sW + ((r - j) * 7 + dx) * 16 + ch0);
#pragma unroll
          for (int c2 = 0; c2 < 4; c2++) acc2[j][c2] += wt2[c2] * v2[c2];
        }
      }
    }
    // write next row into the other buffer
    if (r < 9) {
      float* wb2 = sRow[cur ^ 1];
      *reinterpret_cast<float4*>(wb2 + row_fi(t >> 2, t & 3)) = p0;
      *reinterpret_cast<float4*>(wb2 + row_fi((t + 256) >> 2, t & 3)) = p1;
      if (t < 536 - 512)
        *reinterpret_cast<float4*>(wb2 + row_fi((t + 512) >> 2, t & 3)) = p2;
    }
    __syncthreads();
  }

  // two-round gram; pack+global-store inline per round (R12 structure)
  int colc = lane & 15, kg = lane >> 4;
  f32x4 g00 = {0.f, 0.f, 0.f, 0.f}, g01 = g00, g11 = g00, m0 = g00, m1 = g00;
  bf16x8 ones;
#pragma unroll
  for (int e = 0; e < 8; e++) ones[e] = (short)0x3F80;  // bf16 1.0

#pragma unroll
  for (int rr = 0; rr < 2; rr++) {
    if (rr) __syncthreads();  // all waves done reading previous round's sYT
#pragma unroll
    for (int jj = 0; jj < 2; jj++) {
      int j = rr * 2 + jj;
      size_t ci = ((size_t)(b * Hn + h0 + j) * Wn + w);
      int cidx = jj * 128 + wl;     // cell index within round [0,256)
      uint32_t pkx[4], pkc[4];
#pragma unroll
      for (int q = 0; q < 4; q++)
        pkx[q] = f2bf(xc2[j][q].x) | (f2bf(xc2[j][q].y) << 16);
#pragma unroll
      for (int q = 0; q < 4; q++)
        pkc[q] = f2bf(acc2[j][q].x + sB[ch0 + 2 * q]) |
                 (f2bf(acc2[j][q].y + sB[ch0 + 2 * q + 1]) << 16);
      *reinterpret_cast<uint4*>(ybf + ci * 32 + ch0) =
          make_uint4(pkx[0], pkx[1], pkx[2], pkx[3]);
      *reinterpret_cast<uint4*>(ybf + ci * 32 + 16 + ch0) =
          make_uint4(pkc[0], pkc[1], pkc[2], pkc[3]);
      // LDS transpose: x half -> channels ch0..ch0+7, conv half -> 16+ch0..
#pragma unroll
      for (int q = 0; q < 4; q++) {
        int cA = ch0 + 2 * q, cB = cA + 1;
        sYT[cA * 256 + (cidx ^ ((cA & 7) << 3))] = (short)(uint16_t)(pkx[q] & 0xffffu);
        sYT[cB * 256 + (cidx ^ ((cB & 7) << 3))] = (short)(uint16_t)(pkx[q] >> 16);
        int cC = 16 + cA, cD = 16 + cB;
        sYT[cC * 256 + (cidx ^ ((cC & 7) << 3))] = (short)(uint16_t)(pkc[q] & 0xffffu);
        sYT[cD * 256 + (cidx ^ ((cD & 7) << 3))] = (short)(uint16_t)(pkc[q] >> 16);
      }
    }
    __syncthreads();
    // per-wave gram over this round's cells [wid*64, wid*64+64)
#pragma unroll
    for (int s2 = 0; s2 < 2; s2++) {
      int kbase = wid * 64 + s2 * 32 + kg * 8;
      int chA = colc, chB = 16 + colc;
      bf16x8 f0 = *reinterpret_cast<const bf16x8*>(sYT + chA * 256 + (kbase ^ ((chA & 7) << 3)));
      bf16x8 f1 = *reinterpret_cast<const bf16x8*>(sYT + chB * 256 + (kbase ^ ((chB & 7) << 3)));
      g00 = __builtin_amdgcn_mfma_f32_16x16x32_bf16(f0, f0, g00, 0, 0, 0);
      g01 = __builtin_amdgcn_mfma_f32_16x16x32_bf16(f0, f1, g01, 0, 0, 0);
      g11 = __builtin_amdgcn_mfma_f32_16x16x32_bf16(f1, f1, g11, 0, 0, 0);
      m0  = __builtin_amdgcn_mfma_f32_16x16x32_bf16(f0, ones, m0, 0, 0, 0);
      m1  = __builtin_amdgcn_mfma_f32_16x16x32_bf16(f1, ones, m1, 0, 0, 0);
    }
  }
  if (colc == 0) {
#pragma unroll
    for (int r = 0; r < 4; r++) {
      sMom[wid * 32 + kg * 4 + r] = m0[r];
      sMom[wid * 32 + 16 + kg * 4 + r] = m1[r];
    }
  }
  __syncthreads();  // all waves done reading sYT -> safe to alias as gram
  float* sG = reinterpret_cast<float*>(sYT);  // [4][32][32] = 16KB
  {
    float* sGw = sG + wid * 1024;
#pragma unroll
    for (int r = 0; r < 4; r++) {
      int rr2 = kg * 4 + r;
      sGw[rr2 * 32 + colc] = g00[r];
      sGw[rr2 * 32 + 16 + colc] = g01[r];
      sGw[(16 + rr2) * 32 + 16 + colc] = g11[r];
    }
  }
  __syncthreads();

  float* outp = partials + (size_t)bid * NSTAT;
  for (int e = t; e < NSTAT; e += 256) {
    float a;
    if (e < NPAIR) {
      int ee = e, i = 0;
      while (ee >= (32 - i)) { ee -= (32 - i); i++; }
      int j = i + ee;
      int gi = i * 32 + j;
      a = sG[gi] + sG[1024 + gi] + sG[2048 + gi] + sG[3072 + gi];
    } else {
      int i = e - NPAIR;
      a = sMom[i] + sMom[32 + i] + sMom[64 + i] + sMom[96 + i];
    }
    outp[e] = a;
  }
}

// Fused reduce: each block reduces 4 stats (fp64) -> sred; last block computes
// per-hid BN scale/shift (fc0_b cancels exactly). Release: threadfence + atomicAdd;
// acquire: threadfence after observing prev==NRED-1.
__global__ __launch_bounds__(256) void nca_reduceAB(
    const float* __restrict__ partials, double* __restrict__ sred,
    const float* __restrict__ fc0w, const float* __restrict__ gamma,
    const float* __restrict__ beta, float* __restrict__ ss,
    int* __restrict__ cnt) {
  __shared__ double red[256][4];  // 8KB
  __shared__ double S[NSTAT];     // 4.5KB
  __shared__ int isLast;
  int e4 = blockIdx.x * 4;        // 140 blocks x 4 = 560
  int t = threadIdx.x;
  double a0 = 0.0, a1 = 0.0, a2 = 0.0, a3 = 0.0;
  for (int row = t; row < NGRP; row += 256) {
    float4 v = *reinterpret_cast<const float4*>(partials + (size_t)row * NSTAT + e4);
    a0 += v.x; a1 += v.y; a2 += v.z; a3 += v.w;
  }
  red[t][0] = a0; red[t][1] = a1; red[t][2] = a2; red[t][3] = a3;
  __syncthreads();
  for (int s2 = 128; s2 > 0; s2 >>= 1) {
    if (t < s2) {
#pragma unroll
      for (int q = 0; q < 4; q++) red[t][q] += red[t + s2][q];
    }
    __syncthreads();
  }
  if (t < 4) sred[e4 + t] = red[0][t];
  __threadfence();  // release sred writes
  if (t == 0) {
    int prev = atomicAdd(cnt, 1);
    isLast = (prev == NRED - 1);
  }
  __syncthreads();
  if (!isLast) return;
  __threadfence();  // acquire: all blocks' sred visible
  for (int i = t; i < NSTAT; i += 256) S[i] = sred[i];
  __syncthreads();
  if (t < HIDn) {
    double wv[32];
#pragma unroll
    for (int k = 0; k < 32; k++) wv[k] = (double)fc0w[k * HIDn + t];
    double mean_g = 0.0, q = 0.0;
    int e = 0;
    for (int i = 0; i < 32; i++) {
      mean_g += wv[i] * S[NPAIR + i];
      q += wv[i] * wv[i] * S[e]; e++;
      for (int j = i + 1; j < 32; j++) { q += 2.0 * wv[i] * wv[j] * S[e]; e++; }
    }
    const double invN = 1.0 / (double)NCELLS;
    mean_g *= invN; q *= invN;
    double var = q - mean_g * mean_g;
    double scale = (double)gamma[t] / sqrt(var + 1e-5);
    ss[2 * t]     = (float)scale;
    ss[2 * t + 1] = (float)((double)beta[t] - mean_g * scale);
  }
}

// MFMA update: per wave, 16-cell M-tiles. fc0: 8x mfma_16x16x32_bf16 (K=32);
// BN+relu on f32 accs; repack bf16 via per-wave LDS (XOR swizzle, k-permuted);
// fc1: 4x mfma_16x16x32_bf16 (K=128). Epilogue: dx transposed through hbuf
// (float[16][20], wave-private) -> coalesced float4 residual+store. Grid 1024.
__global__ __launch_bounds__(256) void nca_update_mfma(
    const float* __restrict__ x, const uint16_t* __restrict__ ybf,
    const uint16_t* __restrict__ w0bf, const uint16_t* __restrict__ w1p,
    const float* __restrict__ ssg, float* __restrict__ xout,
    uint32_t fk0, uint32_t fk1) {
  __shared__ __align__(16) short hbuf[4][16 * 128];  // 4KB per wave
  int t = threadIdx.x;
  int lane = t & 63, wid = t >> 6;
  int col = lane & 15, g = lane >> 4;
  short* hb = hbuf[wid];

  bf16x8 b0[8];
#pragma unroll
  for (int nt = 0; nt < 8; nt++) {
    int n = nt * 16 + col;
    b0[nt] = *reinterpret_cast<const bf16x8*>(w0bf + n * 32 + g * 8);
  }
  bf16x8 b2[4];
#pragma unroll
  for (int kk = 0; kk < 4; kk++)
    b2[kk] = *reinterpret_cast<const bf16x8*>(w1p + col * 128 + kk * 32 + g * 8);
  float sc[8], sh[8];
#pragma unroll
  for (int nt = 0; nt < 8; nt++) {
    float2 v = reinterpret_cast<const float2*>(ssg)[nt * 16 + col];
    sc[nt] = v.x; sh[nt] = v.y;
  }

  int mcell = lane >> 2;        // 0..15: cell within tile for coalesced epilogue
  int qch = (lane & 3) * 4;     // channel quad
  uint32_t waveBase = (uint32_t)blockIdx.x * 512u + (uint32_t)wid * 128u;
  for (int grp = 0; grp < 2; grp++) {
    uint32_t grpBase = waveBase + (uint32_t)grp * 64u;
    float mval = cell_mask(fk0, fk1, grpBase + (uint32_t)lane);
#pragma unroll 1
    for (int tt = 0; tt < 4; tt++) {
      uint32_t tb = grpBase + (uint32_t)tt * 16u;
      bf16x8 a0 = *reinterpret_cast<const bf16x8*>(
          ybf + (size_t)(tb + col) * 32 + g * 8);
      f32x4 h[8];
#pragma unroll
      for (int nt = 0; nt < 8; nt++) {
        f32x4 z = {0.f, 0.f, 0.f, 0.f};
        h[nt] = __builtin_amdgcn_mfma_f32_16x16x32_bf16(a0, b0[nt], z, 0, 0, 0);
      }
#pragma unroll
      for (int r = 0; r < 4; r++) {
        int m = g * 4 + r;
        uint32_t u[4];
#pragma unroll
        for (int q = 0; q < 4; q++) {
          float v0 = fmaxf(h[2 * q][r] * sc[2 * q] + sh[2 * q], 0.0f);
          float v1 = fmaxf(h[2 * q + 1][r] * sc[2 * q + 1] + sh[2 * q + 1], 0.0f);
          u[q] = f2bf(v0) | (f2bf(v1) << 16);
        }
        int idx = m * 128 + ((col * 8) ^ ((m & 7) << 3));
        *reinterpret_cast<uint4*>(hb + idx) = make_uint4(u[0], u[1], u[2], u[3]);
      }
      f32x4 dx = {0.f, 0.f, 0.f, 0.f};
#pragma unroll
      for (int kk = 0; kk < 4; kk++) {
        int idx = col * 128 + (((kk * 32) + g * 8) ^ ((col & 7) << 3));
        bf16x8 a2 = *reinterpret_cast<const bf16x8*>(hb + idx);
        dx = __builtin_amdgcn_mfma_f32_16x16x32_bf16(a2, b2[kk], dx, 0, 0, 0);
      }
      // epilogue: transpose dx via hbuf (float[16][20], wave-private), then
      // coalesced float4 residual+store.
      {
        float* tx = reinterpret_cast<float*>(hb);
#pragma unroll
        for (int r = 0; r < 4; r++)
          tx[(g * 4 + r) * 20 + col] = dx[r];
        float4 dxt = *reinterpret_cast<const float4*>(tx + mcell * 20 + qch);
        float4 x4 = *reinterpret_cast<const float4*>(
            x + (size_t)(tb + mcell) * Cn + qch);
        float mk = __shfl(mval, tt * 16 + mcell);
        float4 o4;
        o4.x = x4.x + dxt.x * mk;
        o4.y = x4.y + dxt.y * mk;
        o4.z = x4.z + dxt.z * mk;
        o4.w = x4.w + dxt.w * mk;
        if ((lane & 3) == 0) o4.x = x4.x;  // INPUT_CHANNELS=1: channel 0 preserved
        *reinterpret_cast<float4*>(xout + (size_t)(tb + mcell) * Cn + qch) = o4;
      }
    }
  }
}

extern "C" void kernel_launch(void* const* d_in, const int* in_sizes, int n_in,
                              void* d_out, int out_size, void* d_ws, size_t ws_size,
                              hipStream_t stream) {
  (void)in_sizes; (void)n_in; (void)out_size; (void)ws_size;
  const float* x0    = (const float*)d_in[0];
  const float* p0w   = (const float*)d_in[1];
  const float* p0b   = (const float*)d_in[2];
  const float* fc0w  = (const float*)d_in[3];
  // d_in[4] = fc0_b: cancels exactly in BatchNorm -> unused
  const float* gamma = (const float*)d_in[5];
  const float* beta  = (const float*)d_in[6];
  const float* fc1w  = (const float*)d_in[7];
  // d_in[8] = steps (=10, hardcoded)

  // workspace layout (~70 MB)
  size_t off = 0;
  float* ws_x = (float*)((char*)d_ws + off); off += (size_t)NCELLS * Cn * 4;        // 33.5 MiB
  uint16_t* ws_ybf = (uint16_t*)((char*)d_ws + off); off += (size_t)NCELLS * 32 * 2; // 33.5 MiB
  float* ws_part = (float*)((char*)d_ws + off); off += (size_t)NGRP * NSTAT * 4;    // 2.3 MiB
  double* ws_sred = (double*)((char*)d_ws + off); off += (size_t)NSTAT * 8;
  float* ws_ss = (float*)((char*)d_ws + off); off += (size_t)HIDn * 2 * 4;
  uint16_t* ws_w0bf = (uint16_t*)((char*)d_ws + off); off += 4096 * 2;
  uint16_t* ws_w1p = (uint16_t*)((char*)d_ws + off); off += 2048 * 2;
  int* ws_cnt = (int*)((char*)d_ws + off); off += 16 * 4;
  float* out = (float*)d_out;

  hipMemsetAsync(ws_cnt, 0, 16 * 4, stream);  // per-step reduce counters
  nca_prep<<<24, 256, 0, stream>>>(fc0w, fc1w, ws_w0bf, ws_w1p);

  const float* xin = x0;
  for (int s = 0; s < STEPS; s++) {
    uint32_t fk0 = 0u, fk1 = (uint32_t)s;
    tf2x32(0u, 42u, fk0, fk1);
    float* xo = (((STEPS - 1 - s) & 1) != 0) ? ws_x : out;

    nca_convgram<<<NGRP, 256, 0, stream>>>(xin, p0w, p0b, ws_ybf, ws_part);
    nca_reduceAB<<<NRED, 256, 0, stream>>>(ws_part, ws_sred, fc0w, gamma, beta,
                                           ws_ss, ws_cnt + s);
    nca_update_mfma<<<NCELLS / 512, 256, 0, stream>>>(xin, ws_ybf, ws_w0bf,
                                                      ws_w1p, ws_ss, xo, fk0, fk1);
    xin = xo;
  }
}

// Round 20
// 749.174 us; speedup vs baseline: 1.0933x; 1.0933x over previous
//
#include <hip/hip_runtime.h>
#include <stdint.h>

// BasicNCA2D: 10 steps of depthwise7x7(reflect) -> concat -> fc0 -> BN(batch) -> relu -> fc1 -> masked update.
// B=8,H=256,W=256,C=16,HID=128. steps hardcoded to 10.
// RNG: JAX threefry, jax_threefry_partitionable=True: bits[i] = xor(threefry2x32(key,(0,i))).
//
// R19: revert R18's fused reduceAB (last-block pattern cost +6.8us/step: device-scope
// threadfence across 8 non-coherent XCD L2s + serialized tail). Keep R18's convgram
// tap-captured center-x (FETCH 28->19MB, bit-identical). Separate reduceA/reduceB again.

constexpr int Bn = 8;
constexpr int Hn = 256;
constexpr int Wn = 256;
constexpr int Cn = 16;
constexpr int HIDn = 128;
constexpr int NCELLS = Bn * Hn * Wn;       // 524288
constexpr int NGRP = 1024;                 // fused conv+gram blocks (512 cells each)
constexpr int NPAIR = 528;                 // 32*33/2 unique second moments of y
constexpr int NSTAT = 560;                 // pairs + 32 first moments
constexpr int STEPS = 10;
constexpr int RCELLS = 134;                // staged row cells: 128 + 2*3 halo

typedef __attribute__((ext_vector_type(8))) short bf16x8;
typedef __attribute__((ext_vector_type(4))) float f32x4;
typedef __attribute__((ext_vector_type(2))) float f32x2;

__host__ __device__ inline uint32_t rotl32(uint32_t v, int r) {
  return (v << r) | (v >> (32 - r));
}

// Threefry-2x32, 20 rounds, exactly as jax/_src/prng.py
__host__ __device__ inline void tf2x32(uint32_t k0, uint32_t k1,
                                       uint32_t& x0, uint32_t& x1) {
  uint32_t k2 = k0 ^ k1 ^ 0x1BD11BDAu;
  x0 += k0; x1 += k1;
  x0 += x1; x1 = rotl32(x1, 13); x1 ^= x0;
  x0 += x1; x1 = rotl32(x1, 15); x1 ^= x0;
  x0 += x1; x1 = rotl32(x1, 26); x1 ^= x0;
  x0 += x1; x1 = rotl32(x1,  6); x1 ^= x0;
  x0 += k1; x1 += k2 + 1u;
  x0 += x1; x1 = rotl32(x1, 17); x1 ^= x0;
  x0 += x1; x1 = rotl32(x1, 29); x1 ^= x0;
  x0 += x1; x1 = rotl32(x1, 16); x1 ^= x0;
  x0 += x1; x1 = rotl32(x1, 24); x1 ^= x0;
  x0 += k2; x1 += k0 + 2u;
  x0 += x1; x1 = rotl32(x1, 13); x1 ^= x0;
  x0 += x1; x1 = rotl32(x1, 15); x1 ^= x0;
  x0 += x1; x1 = rotl32(x1, 26); x1 ^= x0;
  x0 += x1; x1 = rotl32(x1,  6); x1 ^= x0;
  x0 += k0; x1 += k1 + 3u;
  x0 += x1; x1 = rotl32(x1, 17); x1 ^= x0;
  x0 += x1; x1 = rotl32(x1, 29); x1 ^= x0;
  x0 += x1; x1 = rotl32(x1, 16); x1 ^= x0;
  x0 += x1; x1 = rotl32(x1, 24); x1 ^= x0;
  x0 += k1; x1 += k2 + 4u;
  x0 += x1; x1 = rotl32(x1, 13); x1 ^= x0;
  x0 += x1; x1 = rotl32(x1, 15); x1 ^= x0;
  x0 += x1; x1 = rotl32(x1, 26); x1 ^= x0;
  x0 += x1; x1 = rotl32(x1,  6); x1 ^= x0;
  x0 += k2; x1 += k0 + 5u;
}

__device__ inline float cell_mask(uint32_t fk0, uint32_t fk1, uint32_t ci) {
  uint32_t a = 0u, b2 = ci;
  tf2x32(fk0, fk1, a, b2);
  uint32_t bits = a ^ b2;
  float u = __uint_as_float((bits >> 9) | 0x3f800000u) - 1.0f;
  return (u > 0.5f) ? 1.0f : 0.0f;
}

// fp32 -> bf16 bits, round-to-nearest-even
__device__ inline uint32_t f2bf(float f) {
  uint32_t u = __float_as_uint(f);
  return (u + 0x7fffu + ((u >> 16) & 1u)) >> 16;
}

// one-time prep:
//  w0bf [n=128][k=32] bf16 : w0bf[n*32+k] = bf16(fc0w[k*128+n])
//  w1p  [c=16][kl=128] bf16: n = (kl&7)*16 + (kl>>3); w1p[c*128+kl] = bf16(fc1w[n*16+c])
__global__ __launch_bounds__(256) void nca_prep(const float* __restrict__ fc0w,
                                                const float* __restrict__ fc1w,
                                                uint16_t* __restrict__ w0bf,
                                                uint16_t* __restrict__ w1p) {
  int i = blockIdx.x * 256 + threadIdx.x;  // 0..6143
  if (i < 4096) {
    int n = i >> 5, k = i & 31;
    w0bf[i] = (uint16_t)f2bf(fc0w[k * HIDn + n]);
  } else {
    int j = i - 4096;
    int c = j >> 7, kl = j & 127;
    int n = (kl & 7) * 16 + (kl >> 3);
    w1p[j] = (uint16_t)f2bf(fc1w[n * 16 + c]);
  }
}

// swizzled float-index of the 16B unit (cell c, quad q) in a staged row
__device__ inline int row_fi(int c, int q) {
  return (((c << 6) + (q << 4)) ^ ((c & 7) << 4)) >> 2;
}

// Fused conv+gram with LDS row staging (R15 structure + R18 tap-capture).
// Block = (b, h-strip of 4, w-half of 128): 512 cells, 256 threads (128 cols x
// 2 ch-halves of 8). Rows staged into a double-buffered swizzled sRow; taps via
// ds_read_b128; conv FMAs packed (v_pk_fma_f32); center-x captured from tap
// registers (r==j+3, dx==3). Gram: two rounds through 16KB sYT.
__global__ __launch_bounds__(256, 4) void nca_convgram(
    const float* __restrict__ x, const float* __restrict__ p0w,
    const float* __restrict__ p0b, uint16_t* __restrict__ ybf,
    float* __restrict__ partials) {
  __shared__ float sW[784];
  __shared__ float sB[16];
  __shared__ __align__(16) float sRow[2][RCELLS * 16];   // 2 x 8576B, swizzled
  __shared__ __align__(16) short sYT[32 * 256];          // 16KB; aliased as f32 gram[4][1024]
  __shared__ float sMom[4 * 32];
  int t = threadIdx.x;
  int lane = t & 63, wid = t >> 6;
  int bid = blockIdx.x;
  int b = bid & 7;               // one image per XCD
  int rest = bid >> 3;           // 0..127
  int h0 = (rest >> 1) * 4;
  int wbase = (rest & 1) * 128;
  for (int i = t; i < 784; i += 256) sW[i] = p0w[i];
  if (t < 16) sB[t] = p0b[t];

  int wl = t & 127;
  int half = t >> 7;             // 0 or 1
  int ch0 = half * 8;
  int w = wbase + wl;
  const float* xb = x + (size_t)b * (Hn * Wn * Cn);

  // global row pointer with vertical reflect
  auto rowptr = [&](int r) -> const float* {
    int hi = h0 - 3 + r;
    hi = (hi < 0) ? -hi : ((hi >= Hn) ? (2 * Hn - 2 - hi) : hi);
    return xb + (size_t)hi * (Wn * Cn);
  };
  // load 16B unit i (cell i>>2, quad i&3) of a row, horizontal reflect
  auto ld16 = [&](const float* xr, int i) -> float4 {
    int c = i >> 2, q = i & 3;
    int wc = wbase - 3 + c;
    wc = (wc < 0) ? -wc : ((wc >= Wn) ? (2 * Wn - 2 - wc) : wc);
    return *reinterpret_cast<const float4*>(xr + (size_t)wc * Cn + q * 4);
  };

  // stage row 0 into buf 0  (536 = 134*4 16B-units, 256 threads: i, i+256, i+512)
  {
    const float* xr = rowptr(0);
    float4 p0 = ld16(xr, t);
    float4 p1 = ld16(xr, t + 256);
    float4 p2;
    if (t < 536 - 512) p2 = ld16(xr, t + 512);
    float* rb = sRow[0];
    *reinterpret_cast<float4*>(rb + row_fi(t >> 2, t & 3)) = p0;
    *reinterpret_cast<float4*>(rb + row_fi((t + 256) >> 2, t & 3)) = p1;
    if (t < 536 - 512)
      *reinterpret_cast<float4*>(rb + row_fi((t + 512) >> 2, t & 3)) = p2;
  }
  __syncthreads();

  f32x2 acc2[4][4];
  f32x2 xc2[4][4];  // center x per cell (captured from taps, bit-identical)
#pragma unroll
  for (int j = 0; j < 4; j++)
#pragma unroll
    for (int c = 0; c < 4; c++) acc2[j][c] = (f32x2){0.0f, 0.0f};

#pragma unroll 1
  for (int r = 0; r < 10; r++) {
    int cur = r & 1;
    // issue next row's global loads early (latency hides under taps+FMA)
    float4 p0, p1, p2;
    if (r < 9) {
      const float* xr = rowptr(r + 1);
      p0 = ld16(xr, t);
      p1 = ld16(xr, t + 256);
      if (t < 536 - 512) p2 = ld16(xr, t + 512);
    }
    // consume current row taps from LDS (packed fp32 FMAs)
    const float* rb = sRow[cur];
#pragma unroll
    for (int dx = 0; dx < 7; dx++) {
      int c = wl + dx;
      float4 va = *reinterpret_cast<const float4*>(rb + row_fi(c, 2 * half));
      float4 vb = *reinterpret_cast<const float4*>(rb + row_fi(c, 2 * half + 1));
      f32x2 v2[4];
      v2[0] = (f32x2){va.x, va.y}; v2[1] = (f32x2){va.z, va.w};
      v2[2] = (f32x2){vb.x, vb.y}; v2[3] = (f32x2){vb.z, vb.w};
      if (dx == 3) {  // center column: capture x for cell j when r == j+3
#pragma unroll
        for (int j = 0; j < 4; j++) {
          if (r == j + 3) {
#pragma unroll
            for (int c2 = 0; c2 < 4; c2++) xc2[j][c2] = v2[c2];
          }
        }
      }
#pragma unroll
      for (int j = 0; j < 4; j++) {
        if (r >= j && r <= j + 6) {  // cell j taps dy = r-j (wave-uniform branch)
          const f32x2* wt2 = reinterpret_cast<const f32x2*>(
              sW + ((r - j) * 7 + dx) * 16 + ch0);
#pragma unroll
          for (int c2 = 0; c2 < 4; c2++) acc2[j][c2] += wt2[c2] * v2[c2];
        }
      }
    }
    // write next row into the other buffer
    if (r < 9) {
      float* wb2 = sRow[cur ^ 1];
      *reinterpret_cast<float4*>(wb2 + row_fi(t >> 2, t & 3)) = p0;
      *reinterpret_cast<float4*>(wb2 + row_fi((t + 256) >> 2, t & 3)) = p1;
      if (t < 536 - 512)
        *reinterpret_cast<float4*>(wb2 + row_fi((t + 512) >> 2, t & 3)) = p2;
    }
    __syncthreads();
  }

  // two-round gram; pack+global-store inline per round (R12 structure)
  int colc = lane & 15, kg = lane >> 4;
  f32x4 g00 = {0.f, 0.f, 0.f, 0.f}, g01 = g00, g11 = g00, m0 = g00, m1 = g00;
  bf16x8 ones;
#pragma unroll
  for (int e = 0; e < 8; e++) ones[e] = (short)0x3F80;  // bf16 1.0

#pragma unroll
  for (int rr = 0; rr < 2; rr++) {
    if (rr) __syncthreads();  // all waves done reading previous round's sYT
#pragma unroll
    for (int jj = 0; jj < 2; jj++) {
      int j = rr * 2 + jj;
      size_t ci = ((size_t)(b * Hn + h0 + j) * Wn + w);
      int cidx = jj * 128 + wl;     // cell index within round [0,256)
      uint32_t pkx[4], pkc[4];
#pragma unroll
      for (int q = 0; q < 4; q++)
        pkx[q] = f2bf(xc2[j][q].x) | (f2bf(xc2[j][q].y) << 16);
#pragma unroll
      for (int q = 0; q < 4; q++)
        pkc[q] = f2bf(acc2[j][q].x + sB[ch0 + 2 * q]) |
                 (f2bf(acc2[j][q].y + sB[ch0 + 2 * q + 1]) << 16);
      *reinterpret_cast<uint4*>(ybf + ci * 32 + ch0) =
          make_uint4(pkx[0], pkx[1], pkx[2], pkx[3]);
      *reinterpret_cast<uint4*>(ybf + ci * 32 + 16 + ch0) =
          make_uint4(pkc[0], pkc[1], pkc[2], pkc[3]);
      // LDS transpose: x half -> channels ch0..ch0+7, conv half -> 16+ch0..
#pragma unroll
      for (int q = 0; q < 4; q++) {
        int cA = ch0 + 2 * q, cB = cA + 1;
        sYT[cA * 256 + (cidx ^ ((cA & 7) << 3))] = (short)(uint16_t)(pkx[q] & 0xffffu);
        sYT[cB * 256 + (cidx ^ ((cB & 7) << 3))] = (short)(uint16_t)(pkx[q] >> 16);
        int cC = 16 + cA, cD = 16 + cB;
        sYT[cC * 256 + (cidx ^ ((cC & 7) << 3))] = (short)(uint16_t)(pkc[q] & 0xffffu);
        sYT[cD * 256 + (cidx ^ ((cD & 7) << 3))] = (short)(uint16_t)(pkc[q] >> 16);
      }
    }
    __syncthreads();
    // per-wave gram over this round's cells [wid*64, wid*64+64)
#pragma unroll
    for (int s2 = 0; s2 < 2; s2++) {
      int kbase = wid * 64 + s2 * 32 + kg * 8;
      int chA = colc, chB = 16 + colc;
      bf16x8 f0 = *reinterpret_cast<const bf16x8*>(sYT + chA * 256 + (kbase ^ ((chA & 7) << 3)));
      bf16x8 f1 = *reinterpret_cast<const bf16x8*>(sYT + chB * 256 + (kbase ^ ((chB & 7) << 3)));
      g00 = __builtin_amdgcn_mfma_f32_16x16x32_bf16(f0, f0, g00, 0, 0, 0);
      g01 = __builtin_amdgcn_mfma_f32_16x16x32_bf16(f0, f1, g01, 0, 0, 0);
      g11 = __builtin_amdgcn_mfma_f32_16x16x32_bf16(f1, f1, g11, 0, 0, 0);
      m0  = __builtin_amdgcn_mfma_f32_16x16x32_bf16(f0, ones, m0, 0, 0, 0);
      m1  = __builtin_amdgcn_mfma_f32_16x16x32_bf16(f1, ones, m1, 0, 0, 0);
    }
  }
  if (colc == 0) {
#pragma unroll
    for (int r = 0; r < 4; r++) {
      sMom[wid * 32 + kg * 4 + r] = m0[r];
      sMom[wid * 32 + 16 + kg * 4 + r] = m1[r];
    }
  }
  __syncthreads();  // all waves done reading sYT -> safe to alias as gram
  float* sG = reinterpret_cast<float*>(sYT);  // [4][32][32] = 16KB
  {
    float* sGw = sG + wid * 1024;
#pragma unroll
    for (int r = 0; r < 4; r++) {
      int rr2 = kg * 4 + r;
      sGw[rr2 * 32 + colc] = g00[r];
      sGw[rr2 * 32 + 16 + colc] = g01[r];
      sGw[(16 + rr2) * 32 + 16 + colc] = g11[r];
    }
  }
  __syncthreads();

  float* outp = partials + (size_t)bid * NSTAT;
  for (int e = t; e < NSTAT; e += 256) {
    float a;
    if (e < NPAIR) {
      int ee = e, i = 0;
      while (ee >= (32 - i)) { ee -= (32 - i); i++; }
      int j = i + ee;
      int gi = i * 32 + j;
      a = sG[gi] + sG[1024 + gi] + sG[2048 + gi] + sG[3072 + gi];
    } else {
      int i = e - NPAIR;
      a = sMom[i] + sMom[32 + i] + sMom[64 + i] + sMom[96 + i];
    }
    outp[e] = a;
  }
}

// Reduce partials across the 1024 groups (fp64), 4 stats/block via float4 reads.
__global__ __launch_bounds__(256) void nca_reduceA(
    const float* __restrict__ partials, double* __restrict__ sred) {
  __shared__ double red[256][4];  // 8KB
  int e4 = blockIdx.x * 4;        // 140 blocks x 4 = 560
  int t = threadIdx.x;
  double a0 = 0.0, a1 = 0.0, a2 = 0.0, a3 = 0.0;
  for (int row = t; row < NGRP; row += 256) {
    float4 v = *reinterpret_cast<const float4*>(partials + (size_t)row * NSTAT + e4);
    a0 += v.x; a1 += v.y; a2 += v.z; a3 += v.w;
  }
  red[t][0] = a0; red[t][1] = a1; red[t][2] = a2; red[t][3] = a3;
  __syncthreads();
  for (int s2 = 128; s2 > 0; s2 >>= 1) {
    if (t < s2) {
#pragma unroll
      for (int q = 0; q < 4; q++) red[t][q] += red[t + s2][q];
    }
    __syncthreads();
  }
  if (t < 4) sred[e4 + t] = red[0][t];
}

// Per-hid BN constants from moments. fc0_b cancels exactly.
__global__ __launch_bounds__(128) void nca_reduceB(
    const double* __restrict__ sred, const float* __restrict__ fc0w,
    const float* __restrict__ gamma, const float* __restrict__ beta,
    float* __restrict__ ss) {
  __shared__ double S[NSTAT];
  int t = threadIdx.x;
  for (int i = t; i < NSTAT; i += 128) S[i] = sred[i];
  __syncthreads();
  double wv[32];
#pragma unroll
  for (int k = 0; k < 32; k++) wv[k] = (double)fc0w[k * HIDn + t];
  double mean_g = 0.0, q = 0.0;
  int e = 0;
  for (int i = 0; i < 32; i++) {
    mean_g += wv[i] * S[NPAIR + i];
    q += wv[i] * wv[i] * S[e]; e++;
    for (int j = i + 1; j < 32; j++) { q += 2.0 * wv[i] * wv[j] * S[e]; e++; }
  }
  const double invN = 1.0 / (double)NCELLS;
  mean_g *= invN; q *= invN;
  double var = q - mean_g * mean_g;
  double scale = (double)gamma[t] / sqrt(var + 1e-5);
  ss[2 * t]     = (float)scale;
  ss[2 * t + 1] = (float)((double)beta[t] - mean_g * scale);
}

// MFMA update: per wave, 16-cell M-tiles. fc0: 8x mfma_16x16x32_bf16 (K=32);
// BN+relu on f32 accs; repack bf16 via per-wave LDS (XOR swizzle, k-permuted);
// fc1: 4x mfma_16x16x32_bf16 (K=128). Epilogue: dx transposed through hbuf
// (float[16][20], wave-private) -> coalesced float4 residual+store. Grid 1024.
__global__ __launch_bounds__(256) void nca_update_mfma(
    const float* __restrict__ x, const uint16_t* __restrict__ ybf,
    const uint16_t* __restrict__ w0bf, const uint16_t* __restrict__ w1p,
    const float* __restrict__ ssg, float* __restrict__ xout,
    uint32_t fk0, uint32_t fk1) {
  __shared__ __align__(16) short hbuf[4][16 * 128];  // 4KB per wave
  int t = threadIdx.x;
  int lane = t & 63, wid = t >> 6;
  int col = lane & 15, g = lane >> 4;
  short* hb = hbuf[wid];

  bf16x8 b0[8];
#pragma unroll
  for (int nt = 0; nt < 8; nt++) {
    int n = nt * 16 + col;
    b0[nt] = *reinterpret_cast<const bf16x8*>(w0bf + n * 32 + g * 8);
  }
  bf16x8 b2[4];
#pragma unroll
  for (int kk = 0; kk < 4; kk++)
    b2[kk] = *reinterpret_cast<const bf16x8*>(w1p + col * 128 + kk * 32 + g * 8);
  float sc[8], sh[8];
#pragma unroll
  for (int nt = 0; nt < 8; nt++) {
    float2 v = reinterpret_cast<const float2*>(ssg)[nt * 16 + col];
    sc[nt] = v.x; sh[nt] = v.y;
  }

  int mcell = lane >> 2;        // 0..15: cell within tile for coalesced epilogue
  int qch = (lane & 3) * 4;     // channel quad
  uint32_t waveBase = (uint32_t)blockIdx.x * 512u + (uint32_t)wid * 128u;
  for (int grp = 0; grp < 2; grp++) {
    uint32_t grpBase = waveBase + (uint32_t)grp * 64u;
    float mval = cell_mask(fk0, fk1, grpBase + (uint32_t)lane);
#pragma unroll 1
    for (int tt = 0; tt < 4; tt++) {
      uint32_t tb = grpBase + (uint32_t)tt * 16u;
      bf16x8 a0 = *reinterpret_cast<const bf16x8*>(
          ybf + (size_t)(tb + col) * 32 + g * 8);
      f32x4 h[8];
#pragma unroll
      for (int nt = 0; nt < 8; nt++) {
        f32x4 z = {0.f, 0.f, 0.f, 0.f};
        h[nt] = __builtin_amdgcn_mfma_f32_16x16x32_bf16(a0, b0[nt], z, 0, 0, 0);
      }
#pragma unroll
      for (int r = 0; r < 4; r++) {
        int m = g * 4 + r;
        uint32_t u[4];
#pragma unroll
        for (int q = 0; q < 4; q++) {
          float v0 = fmaxf(h[2 * q][r] * sc[2 * q] + sh[2 * q], 0.0f);
          float v1 = fmaxf(h[2 * q + 1][r] * sc[2 * q + 1] + sh[2 * q + 1], 0.0f);
          u[q] = f2bf(v0) | (f2bf(v1) << 16);
        }
        int idx = m * 128 + ((col * 8) ^ ((m & 7) << 3));
        *reinterpret_cast<uint4*>(hb + idx) = make_uint4(u[0], u[1], u[2], u[3]);
      }
      f32x4 dx = {0.f, 0.f, 0.f, 0.f};
#pragma unroll
      for (int kk = 0; kk < 4; kk++) {
        int idx = col * 128 + (((kk * 32) + g * 8) ^ ((col & 7) << 3));
        bf16x8 a2 = *reinterpret_cast<const bf16x8*>(hb + idx);
        dx = __builtin_amdgcn_mfma_f32_16x16x32_bf16(a2, b2[kk], dx, 0, 0, 0);
      }
      // epilogue: transpose dx via hbuf (float[16][20], wave-private), then
      // coalesced float4 residual+store.
      {
        float* tx = reinterpret_cast<float*>(hb);
#pragma unroll
        for (int r = 0; r < 4; r++)
          tx[(g * 4 + r) * 20 + col] = dx[r];
        float4 dxt = *reinterpret_cast<const float4*>(tx + mcell * 20 + qch);
        float4 x4 = *reinterpret_cast<const float4*>(
            x + (size_t)(tb + mcell) * Cn + qch);
        float mk = __shfl(mval, tt * 16 + mcell);
        float4 o4;
        o4.x = x4.x + dxt.x * mk;
        o4.y = x4.y + dxt.y * mk;
        o4.z = x4.z + dxt.z * mk;
        o4.w = x4.w + dxt.w * mk;
        if ((lane & 3) == 0) o4.x = x4.x;  // INPUT_CHANNELS=1: channel 0 preserved
        *reinterpret_cast<float4*>(xout + (size_t)(tb + mcell) * Cn + qch) = o4;
      }
    }
  }
}

extern "C" void kernel_launch(void* const* d_in, const int* in_sizes, int n_in,
                              void* d_out, int out_size, void* d_ws, size_t ws_size,
                              hipStream_t stream) {
  (void)in_sizes; (void)n_in; (void)out_size; (void)ws_size;
  const float* x0    = (const float*)d_in[0];
  const float* p0w   = (const float*)d_in[1];
  const float* p0b   = (const float*)d_in[2];
  const float* fc0w  = (const float*)d_in[3];
  // d_in[4] = fc0_b: cancels exactly in BatchNorm -> unused
  const float* gamma = (const float*)d_in[5];
  const float* beta  = (const float*)d_in[6];
  const float* fc1w  = (const float*)d_in[7];
  // d_in[8] = steps (=10, hardcoded)

  // workspace layout (~70 MB)
  size_t off = 0;
  float* ws_x = (float*)((char*)d_ws + off); off += (size_t)NCELLS * Cn * 4;        // 33.5 MiB
  uint16_t* ws_ybf = (uint16_t*)((char*)d_ws + off); off += (size_t)NCELLS * 32 * 2; // 33.5 MiB
  float* ws_part = (float*)((char*)d_ws + off); off += (size_t)NGRP * NSTAT * 4;    // 2.3 MiB
  double* ws_sred = (double*)((char*)d_ws + off); off += (size_t)NSTAT * 8;
  float* ws_ss = (float*)((char*)d_ws + off); off += (size_t)HIDn * 2 * 4;
  uint16_t* ws_w0bf = (uint16_t*)((char*)d_ws + off); off += 4096 * 2;
  uint16_t* ws_w1p = (uint16_t*)((char*)d_ws + off); off += 2048 * 2;
  float* out = (float*)d_out;

  nca_prep<<<24, 256, 0, stream>>>(fc0w, fc1w, ws_w0bf, ws_w1p);

  const float* xin = x0;
  for (int s = 0; s < STEPS; s++) {
    uint32_t fk0 = 0u, fk1 = (uint32_t)s;
    tf2x32(0u, 42u, fk0, fk1);
    float* xo = (((STEPS - 1 - s) & 1) != 0) ? ws_x : out;

    nca_convgram<<<NGRP, 256, 0, stream>>>(xin, p0w, p0b, ws_ybf, ws_part);
    nca_reduceA<<<140, 256, 0, stream>>>(ws_part, ws_sred);
    nca_reduceB<<<1, 128, 0, stream>>>(ws_sred, fc0w, gamma, beta, ws_ss);
    nca_update_mfma<<<NCELLS / 512, 256, 0, stream>>>(xin, ws_ybf, ws_w0bf,
                                                      ws_w1p, ws_ss, xo, fk0, fk1);
    xin = xo;
  }
}